// Round 3
// baseline (323.864 us; speedup 1.0000x reference)
//
#include <hip/hip_runtime.h>
#include <hip/hip_bf16.h>

#define IN_DIM   128
#define HIDDEN   128
#define KDIM     256          // 2*IN_DIM
#define BLOCK_E  128
#define NTHREADS 512
#define LDB      264          // padded LDS row length in bf16 (264*2 = 528 B = 33*16B)

typedef __attribute__((ext_vector_type(8))) short  bf16x8;
typedef __attribute__((ext_vector_type(4))) float  f32x4;

__device__ __forceinline__ unsigned short f2bf(float f) {
    union { __hip_bfloat16 h; unsigned short u; } cv;
    cv.h = __float2bfloat16(f);
    return cv.u;
}

// Pre-pass A: W1 [256][128] f32 -> W1T [128][256] bf16 (K-contiguous rows)
__global__ void w1_transpose_bf16(const float* __restrict__ W1,
                                  unsigned short* __restrict__ W1T) {
    int o = blockIdx.x * blockDim.x + threadIdx.x;
    if (o >= HIDDEN * KDIM) return;
    int n = o >> 8;      // 0..127 (hidden)
    int k = o & 255;     // 0..255 (concat-K)
    W1T[o] = f2bf(W1[k * HIDDEN + n]);
}

// Pre-pass B: f32 embedding tables -> bf16 tables (halves gather traffic).
// Each thread converts 8 contiguous floats -> 8 bf16 (16B store).
__global__ void tables_to_bf16(const float* __restrict__ pat,
                               const float* __restrict__ cond,
                               unsigned short* __restrict__ pat_bf,
                               unsigned short* __restrict__ cond_bf,
                               int n_vec_per_table) {
    int id = blockIdx.x * blockDim.x + threadIdx.x;
    int which = (id >= n_vec_per_table);
    int v = which ? id - n_vec_per_table : id;
    if (v >= n_vec_per_table) return;
    const float* src = which ? cond : pat;
    unsigned short* dst = which ? cond_bf : pat_bf;
    long long base = (long long)v * 8;
    float4 x = *(const float4*)(src + base);
    float4 y = *(const float4*)(src + base + 4);
    unsigned short hv[8];
    hv[0] = f2bf(x.x); hv[1] = f2bf(x.y); hv[2] = f2bf(x.z); hv[3] = f2bf(x.w);
    hv[4] = f2bf(y.x); hv[5] = f2bf(y.y); hv[6] = f2bf(y.z); hv[7] = f2bf(y.w);
    *(uint4*)(dst + base) = *(uint4*)hv;
}

__global__ __launch_bounds__(NTHREADS, 4)
void link_mlp_kernel(const float* __restrict__ pat,
                     const float* __restrict__ cond,
                     const unsigned short* __restrict__ tbl_p,   // bf16 tables (or null)
                     const unsigned short* __restrict__ tbl_c,
                     const int* __restrict__ eidx,               // int32 on device
                     const unsigned short* __restrict__ W1T,
                     const float* __restrict__ b1,
                     const float* __restrict__ W2,
                     const float* __restrict__ b2,
                     float* __restrict__ out,
                     int E, int n_nodes)
{
    __shared__ unsigned short sA[BLOCK_E][LDB];   // gathered concat(src,dst) bf16
    __shared__ int   sh_idx[2 * BLOCK_E];
    __shared__ float sh_logit[BLOCK_E];

    const int t  = threadIdx.x;
    const int e0 = blockIdx.x * BLOCK_E;

    // ---- edge indices (tail-clamped + fault insurance) ----
    if (t < 2 * BLOCK_E) {
        int i = t;
        int e = e0 + (i & (BLOCK_E - 1));
        int v = 0;
        if (e < E) v = (i < BLOCK_E) ? eidx[e] : eidx[E + e];
        v = min(max(v, 0), n_nodes - 1);
        sh_idx[i] = v;
    }
    if (t < BLOCK_E) sh_logit[t] = 0.f;

    const int w    = t >> 6;        // wave 0..7 -> owns output cols w*16..w*16+15
    const int lane = t & 63;
    const int l15  = lane & 15;
    const int l4   = lane >> 4;     // 0..3

    // ---- per-wave W1T column-slice -> persistent registers (32 VGPRs) ----
    // lane l: B-frag row (=output col) w*16+l15, k = ks*32 + l4*8 .. +8
    bf16x8 bfr[8];
    {
        const unsigned short* bp = W1T + (w * 16 + l15) * KDIM + l4 * 8;
        #pragma unroll
        for (int ks = 0; ks < 8; ++ks)
            bfr[ks] = *(const bf16x8*)(bp + ks * 32);
    }

    __syncthreads();

    const int lane32 = t & 31;
    const int grp    = t >> 5;      // 0..15

    // ---- gather edge rows into sA ----
    if (tbl_p) {
        // bf16 tables: row-half = 128 bf16 = 256B = 16 lanes x 16B; 2 per 32-lane group
        const int lane16 = lane32 & 15;
        const int sub    = lane32 >> 4;
        #pragma unroll
        for (int it = 0; it < 8; ++it) {
            int rh   = it * 32 + grp * 2 + sub;   // == half*128 + e
            int half = rh >> 7;
            int e    = rh & (BLOCK_E - 1);
            int node = sh_idx[rh];
            const unsigned short* tbl = half ? tbl_c : tbl_p;
            uint4 v = *(const uint4*)(tbl + (long long)node * IN_DIM + lane16 * 8);
            *(uint4*)&sA[e][half * IN_DIM + lane16 * 8] = v;
        }
    } else {
        // f32 fallback: row-half = 128 f32 = 512B = 32 lanes x 16B
        #pragma unroll
        for (int it = 0; it < 16; ++it) {
            int rh   = it * 16 + grp;
            int half = rh >> 7;
            int e    = rh & (BLOCK_E - 1);
            int node = sh_idx[half * BLOCK_E + e];
            const float4* srcp =
                (const float4*)((half ? cond : pat) + (long long)node * IN_DIM);
            float4 v = srcp[lane32];
            ushort4 hv;
            hv.x = f2bf(v.x); hv.y = f2bf(v.y); hv.z = f2bf(v.z); hv.w = f2bf(v.w);
            *(ushort4*)&sA[e][half * IN_DIM + lane32 * 4] = hv;
        }
    }
    __syncthreads();

    // ---- MFMA: each wave computes [128 x 16] slice; A from LDS, B in regs ----
    f32x4 acc[8];
    #pragma unroll
    for (int mt = 0; mt < 8; ++mt) acc[mt] = (f32x4){0.f, 0.f, 0.f, 0.f};

    #pragma unroll
    for (int ks = 0; ks < 8; ++ks) {
        const int kof = ks * 32 + l4 * 8;
        #pragma unroll
        for (int mt = 0; mt < 8; ++mt) {
            bf16x8 a = *(const bf16x8*)&sA[mt * 16 + l15][kof];
            acc[mt] = __builtin_amdgcn_mfma_f32_16x16x32_bf16(a, bfr[ks], acc[mt], 0, 0, 0);
        }
    }

    // ---- layer 2: +b1, relu, dot W2 slice, reduce over 16 cols ----
    const float b1v = b1[w * 16 + l15];
    const float w2v = W2[w * 16 + l15];
    #pragma unroll
    for (int mt = 0; mt < 8; ++mt) {
        float part[4];
        #pragma unroll
        for (int r = 0; r < 4; ++r)
            part[r] = fmaxf(acc[mt][r] + b1v, 0.f) * w2v;
        #pragma unroll
        for (int off = 1; off < 16; off <<= 1)
            #pragma unroll
            for (int r = 0; r < 4; ++r)
                part[r] += __shfl_xor(part[r], off, 64);
        if (l15 == 0) {
            #pragma unroll
            for (int r = 0; r < 4; ++r)
                atomicAdd(&sh_logit[mt * 16 + l4 * 4 + r], part[r]);
        }
    }
    __syncthreads();

    // ---- sigmoid + store ----
    if (t < BLOCK_E) {
        int e = e0 + t;
        if (e < E) {
            float x = sh_logit[t] + b2[0];
            out[e] = 1.f / (1.f + __expf(-x));
        }
    }
}

extern "C" void kernel_launch(void* const* d_in, const int* in_sizes, int n_in,
                              void* d_out, int out_size, void* d_ws, size_t ws_size,
                              hipStream_t stream) {
    const float* pat  = (const float*)d_in[0];
    const float* cond = (const float*)d_in[1];
    const int*   eidx = (const int*)d_in[2];     // int64 in reference -> int32 on device
    const float* W1   = (const float*)d_in[3];
    const float* b1   = (const float*)d_in[4];
    const float* W2   = (const float*)d_in[5];
    const float* b2   = (const float*)d_in[6];
    float*       out  = (float*)d_out;

    const int E       = in_sizes[2] / 2;
    const int n_nodes = in_sizes[0] / IN_DIM;

    // ws layout: [0,64K) W1T bf16 | pat_bf | cond_bf
    unsigned short* W1T = (unsigned short*)d_ws;
    const size_t tbl_bytes = (size_t)n_nodes * IN_DIM * 2;
    unsigned short* pat_bf  = (unsigned short*)((char*)d_ws + 65536);
    unsigned short* cond_bf = (unsigned short*)((char*)d_ws + 65536 + tbl_bytes);
    const bool use_tbl = ws_size >= 65536 + 2 * tbl_bytes;

    w1_transpose_bf16<<<(HIDDEN * KDIM + 255) / 256, 256, 0, stream>>>(W1, W1T);

    if (use_tbl) {
        const int n_vec = n_nodes * IN_DIM / 8;   // per table
        tables_to_bf16<<<(2 * n_vec + 255) / 256, 256, 0, stream>>>(
            pat, cond, pat_bf, cond_bf, n_vec);
    }

    const int nblocks = (E + BLOCK_E - 1) / BLOCK_E;
    link_mlp_kernel<<<nblocks, NTHREADS, 0, stream>>>(
        pat, cond,
        use_tbl ? pat_bf : nullptr, use_tbl ? cond_bf : nullptr,
        eidx, W1T, b1, W2, b2, out, E, n_nodes);
}

// Round 4
// 190.681 us; speedup vs baseline: 1.6985x; 1.6985x over previous
//
#include <hip/hip_runtime.h>
#include <hip/hip_bf16.h>

#define IN_DIM   128
#define HIDDEN   128
#define KDIM     256          // 2*IN_DIM
#define TILE_E   32           // edges per wave-tile
#define NTHREADS 512
#define LDBW     264          // sB row pitch in bf16 (528 B = 132 dw == 4 mod 32 banks)

typedef __attribute__((ext_vector_type(8)))  short bf16x8;
typedef __attribute__((ext_vector_type(16))) float f32x16;

__device__ __forceinline__ unsigned short f2bf(float f) {
    union { __hip_bfloat16 h; unsigned short u; } cv;
    cv.h = __float2bfloat16(f);
    return cv.u;
}

// Fused prep: bf16 copies of both embedding tables + W1 transpose->bf16.
// unit = 8 elements. Layout: [0,nvec) pat | [nvec,2nvec) cond | w1t units.
__global__ void prep_kernel(const float* __restrict__ pat,
                            const float* __restrict__ cond,
                            const float* __restrict__ W1,
                            unsigned short* __restrict__ pat_bf,
                            unsigned short* __restrict__ cond_bf,
                            unsigned short* __restrict__ W1T,
                            int n_vec, int do_tables) {
    const int w1_units = HIDDEN * KDIM / 8;         // 4096
    const long long total = do_tables ? (2LL * n_vec + w1_units) : w1_units;
    const long long stride = (long long)gridDim.x * blockDim.x;
    for (long long u = blockIdx.x * (long long)blockDim.x + threadIdx.x;
         u < total; u += stride) {
        if (do_tables && u < 2LL * n_vec) {
            int which = (u >= n_vec);
            long long v = which ? u - n_vec : u;
            const float* src = which ? cond : pat;
            unsigned short* dst = which ? cond_bf : pat_bf;
            long long base = v * 8;
            float4 x = *(const float4*)(src + base);
            float4 y = *(const float4*)(src + base + 4);
            unsigned short hv[8];
            hv[0]=f2bf(x.x); hv[1]=f2bf(x.y); hv[2]=f2bf(x.z); hv[3]=f2bf(x.w);
            hv[4]=f2bf(y.x); hv[5]=f2bf(y.y); hv[6]=f2bf(y.z); hv[7]=f2bf(y.w);
            *(uint4*)(dst + base) = *(uint4*)hv;
        } else {
            int idx = (int)(u - (do_tables ? 2LL * n_vec : 0));  // 0..4095
            int c  = idx >> 5;        // hidden col 0..127
            int k0 = (idx & 31) * 8;  // k offset
            unsigned short hv[8];
            #pragma unroll
            for (int j = 0; j < 8; ++j)
                hv[j] = f2bf(W1[(k0 + j) * HIDDEN + c]);
            *(uint4*)(W1T + c * KDIM + k0) = *(uint4*)hv;
        }
    }
}

__global__ __launch_bounds__(NTHREADS, 4)
void link_mlp_kernel(const float* __restrict__ pat,
                     const float* __restrict__ cond,
                     const unsigned short* __restrict__ tbl_p,   // bf16 tables (or null)
                     const unsigned short* __restrict__ tbl_c,
                     const int* __restrict__ eidx,               // int32 on device
                     const unsigned short* __restrict__ W1T,
                     const float* __restrict__ b1,
                     const float* __restrict__ W2,
                     const float* __restrict__ b2,
                     float* __restrict__ out,
                     int E, int n_nodes, int ntiles)
{
    __shared__ unsigned short sB[HIDDEN * LDBW];   // W1T, padded pitch
    __shared__ float sLog[8][TILE_E];

    const int t = threadIdx.x;

    // ---- stage W1T -> sB once (64 KB, 16B chunks) ----
    #pragma unroll
    for (int it = 0; it < 8; ++it) {
        int ci = it * NTHREADS + t;          // 0..4095
        int c = ci >> 5, j = ci & 31;
        *(uint4*)&sB[c * LDBW + j * 8] = *(const uint4*)(W1T + c * KDIM + j * 8);
    }
    __syncthreads();

    const int w    = t >> 6;
    const int lane = t & 63;
    const int c32  = lane & 31;
    const int hi   = lane >> 5;

    // hoisted epilogue constants: lane's 4 hidden cols
    float b1v[4], w2v[4];
    #pragma unroll
    for (int nt = 0; nt < 4; ++nt) {
        int col = nt * 32 + c32;
        b1v[nt] = b1[col];
        w2v[nt] = W2[col];
    }
    const float b2v = b2[0];

    const int wslots = gridDim.x * (NTHREADS / 64);

    for (int tile = blockIdx.x * (NTHREADS / 64) + w; tile < ntiles; tile += wslots) {
        const int e  = tile * TILE_E + c32;
        const int eC = min(e, E - 1);
        int np = eidx[eC];     np = min(max(np, 0), n_nodes - 1);
        int nc = eidx[E + eC]; nc = min(max(nc, 0), n_nodes - 1);

        f32x16 acc[4];
        #pragma unroll
        for (int nt = 0; nt < 4; ++nt)
            acc[nt] = (f32x16){0.f,0.f,0.f,0.f,0.f,0.f,0.f,0.f,
                               0.f,0.f,0.f,0.f,0.f,0.f,0.f,0.f};

        if (tbl_p) {
            const unsigned short* bp = tbl_p + np * IN_DIM + hi * 8;
            const unsigned short* bc = tbl_c + nc * IN_DIM + hi * 8;
            #pragma unroll
            for (int ksb = 0; ksb < 4; ++ksb) {
                bf16x8 a[4];
                #pragma unroll
                for (int j = 0; j < 4; ++j) {
                    int ks = ksb * 4 + j;     // K-step: k = ks*16 + hi*8
                    const unsigned short* src =
                        (ks < 8) ? (bp + ks * 16) : (bc + (ks - 8) * 16);
                    a[j] = *(const bf16x8*)src;
                }
                #pragma unroll
                for (int j = 0; j < 4; ++j) {
                    int ks = ksb * 4 + j;
                    #pragma unroll
                    for (int nt = 0; nt < 4; ++nt) {
                        bf16x8 b = *(const bf16x8*)
                            &sB[(nt * 32 + c32) * LDBW + ks * 16 + hi * 8];
                        acc[nt] = __builtin_amdgcn_mfma_f32_32x32x16_bf16(
                            a[j], b, acc[nt], 0, 0, 0);
                    }
                }
            }
        } else {
            // f32 fallback: convert in-register
            const float* fp = pat  + (long long)np * IN_DIM + hi * 8;
            const float* fc = cond + (long long)nc * IN_DIM + hi * 8;
            #pragma unroll
            for (int ksb = 0; ksb < 4; ++ksb) {
                bf16x8 a[4];
                #pragma unroll
                for (int j = 0; j < 4; ++j) {
                    int ks = ksb * 4 + j;
                    const float* src = (ks < 8) ? (fp + ks * 16) : (fc + (ks - 8) * 16);
                    float4 x = *(const float4*)src;
                    float4 y = *(const float4*)(src + 4);
                    unsigned short hv[8];
                    hv[0]=f2bf(x.x); hv[1]=f2bf(x.y); hv[2]=f2bf(x.z); hv[3]=f2bf(x.w);
                    hv[4]=f2bf(y.x); hv[5]=f2bf(y.y); hv[6]=f2bf(y.z); hv[7]=f2bf(y.w);
                    a[j] = *(bf16x8*)hv;
                }
                #pragma unroll
                for (int j = 0; j < 4; ++j) {
                    int ks = ksb * 4 + j;
                    #pragma unroll
                    for (int nt = 0; nt < 4; ++nt) {
                        bf16x8 b = *(const bf16x8*)
                            &sB[(nt * 32 + c32) * LDBW + ks * 16 + hi * 8];
                        acc[nt] = __builtin_amdgcn_mfma_f32_32x32x16_bf16(
                            a[j], b, acc[nt], 0, 0, 0);
                    }
                }
            }
        }

        // ---- epilogue: relu + W2 dot, butterfly over 32 cols, bounce, store ----
        float p[16];
        #pragma unroll
        for (int r = 0; r < 16; ++r) {
            float s = 0.f;
            #pragma unroll
            for (int nt = 0; nt < 4; ++nt)
                s += fmaxf(acc[nt][r] + b1v[nt], 0.f) * w2v[nt];
            p[r] = s;
        }
        #pragma unroll
        for (int off = 1; off < 32; off <<= 1)
            #pragma unroll
            for (int r = 0; r < 16; ++r)
                p[r] += __shfl_xor(p[r], off, 64);
        if (c32 == 0) {
            #pragma unroll
            for (int r = 0; r < 16; ++r)
                sLog[w][(r & 3) + 8 * (r >> 2) + 4 * hi] = p[r];
        }
        // same-wave write->read; compiler inserts lgkmcnt wait
        float x  = sLog[w][c32] + b2v;
        float sg = 1.f / (1.f + __expf(-x));
        if (hi == 0 && e < E) out[e] = sg;
    }
}

extern "C" void kernel_launch(void* const* d_in, const int* in_sizes, int n_in,
                              void* d_out, int out_size, void* d_ws, size_t ws_size,
                              hipStream_t stream) {
    const float* pat  = (const float*)d_in[0];
    const float* cond = (const float*)d_in[1];
    const int*   eidx = (const int*)d_in[2];     // int64 in reference -> int32 on device
    const float* W1   = (const float*)d_in[3];
    const float* b1   = (const float*)d_in[4];
    const float* W2   = (const float*)d_in[5];
    const float* b2   = (const float*)d_in[6];
    float*       out  = (float*)d_out;

    const int E       = in_sizes[2] / 2;
    const int n_nodes = in_sizes[0] / IN_DIM;
    const int ntiles  = (E + TILE_E - 1) / TILE_E;

    // ws layout: [0,64K) W1T bf16 | pat_bf | cond_bf
    unsigned short* W1T = (unsigned short*)d_ws;
    const size_t tbl_bytes = (size_t)n_nodes * IN_DIM * 2;
    unsigned short* pat_bf  = (unsigned short*)((char*)d_ws + 65536);
    unsigned short* cond_bf = (unsigned short*)((char*)d_ws + 65536 + tbl_bytes);
    const bool use_tbl = ws_size >= 65536 + 2 * tbl_bytes;

    const int n_vec = n_nodes * IN_DIM / 8;   // vec8 units per table
    prep_kernel<<<2048, 256, 0, stream>>>(pat, cond, W1, pat_bf, cond_bf, W1T,
                                          n_vec, use_tbl ? 1 : 0);

    const int nblocks = 512;                  // 2 blocks/CU target, grid-stride waves
    link_mlp_kernel<<<nblocks, NTHREADS, 0, stream>>>(
        pat, cond,
        use_tbl ? pat_bf : nullptr, use_tbl ? cond_bf : nullptr,
        eidx, W1T, b1, W2, b2, out, E, n_nodes, ntiles);
}